// Round 4
// baseline (157.504 us; speedup 1.0000x reference)
//
#include <hip/hip_runtime.h>

// Problem constants (match reference)
#define T_TICKS 128
#define NCH     1536
#define NCPAIR  10000
#define NCROSS  30000
#define E_EDGES 120000
#define TG      4               // ticks per thread
#define TGB     16              // ticks per block (4 tick-lanes x TG)
#define NCHUNK  (T_TICKS / TGB) // 8 tick chunks
#define CAP     32              // bucket capacity (deg ~ Poisson(4))
#define BNODE   64              // nodes per k_gat block
#define NBLKN   ((NCROSS + BNODE - 1) / BNODE)  // 469
#define PREP_ITEMS (NCROSS + E_EDGES)

// ---------------- prep: per-node tick-static scalars + edge scatter ----------
// h(t)·a = hB + x[chA][t]*hA1 + x[chB][t]*hB1 + t*hT with hA1/hB1/hT global
// scalars. Per node: c4 = {sB, pB, dB, chA|chB<<16} -- ONE 16-B record serves
// both "own" and "neighbor" roles. Bucket node-major [n][CAP] (128-B rows).

__global__ void k_prep(const float* __restrict__ x,
                       const int* __restrict__ c0, const int* __restrict__ c1,
                       const int* __restrict__ c2,
                       const int* __restrict__ g01, const int* __restrict__ g12,
                       const int* __restrict__ g20,
                       const float* __restrict__ r01,
                       const float* __restrict__ r12,
                       const float* __restrict__ r20,
                       const float* __restrict__ Wg,
                       const float* __restrict__ bg,
                       const float* __restrict__ as_,
                       const float* __restrict__ ad_,
                       const float* __restrict__ Wm,
                       const int* __restrict__ e_src,
                       const int* __restrict__ e_dst,
                       int* __restrict__ counts,
                       int* __restrict__ bucket,
                       float4* __restrict__ c4) {
    const int gid = blockIdx.x * 256 + threadIdx.x;
    if (gid < NCROSS) {
        const int n = gid;
        int iA, iB, m;
        float pA, pB;
        const int* cA;
        const int* cB;
        const float* ray;
        if (n < NCPAIR) {
            m = n; cA = c0; cB = c1; pA = 0.f; pB = 1.f; ray = r01;
            iA = g01[2 * m]; iB = g01[2 * m + 1];
        } else if (n < 2 * NCPAIR) {
            m = n - NCPAIR; cA = c1; cB = c2; pA = 1.f; pB = 2.f; ray = r12;
            iA = g12[2 * m]; iB = g12[2 * m + 1];
        } else {
            m = n - 2 * NCPAIR; cA = c2; cB = c0; pA = 2.f; pB = 0.f; ray = r20;
            iA = g20[2 * m]; iB = g20[2 * m + 1];
        }
        const int chA = cA[iA];
        const int chB = cB[iB];
        const float rx = ray[2 * m];
        const float ry = ray[2 * m + 1];

        float base[4];
#pragma unroll
        for (int c = 0; c < 4; c++) {
            base[c] = bg[c]
                    + (float)iA  * Wg[1 * 4 + c] + (float)chA * Wg[2 * 4 + c]
                    + pA         * Wg[4 * 4 + c]
                    + (float)iB  * Wg[6 * 4 + c] + (float)chB * Wg[7 * 4 + c]
                    + pB         * Wg[9 * 4 + c]
                    + rx         * Wg[10 * 4 + c] + ry * Wg[11 * 4 + c];
        }
        float sB = 0.f, dB = 0.f, pBs = 0.f;
#pragma unroll
        for (int c = 0; c < 4; c++) {
            sB  = fmaf(base[c], as_[c], sB);
            dB  = fmaf(base[c], ad_[c], dB);
            pBs = fmaf(base[c], Wm[c], pBs);
        }
        c4[n] = make_float4(sB, pBs, dB, __int_as_float(chA | (chB << 16)));
    } else if (gid < PREP_ITEMS) {
        const int i = gid - NCROSS;
        const int s = e_src[i];
        const int d = e_dst[i];
        const int slot = atomicAdd(&counts[d], 1);
        if (slot < CAP) bucket[(size_t)d * CAP + slot] = s;
    }
}

// ---------------- GAT aggregation + MLP + sigmoid ----------------------------
// Block = 64 nodes x 4 tick-lanes, NO degree sort: counts[n], c4[n] and the
// bucket int4 row are address-independent -> all issue at cycle 0. Neighbor
// indices clamped to [0,NCROSS) so every load is unconditional (poison-safe,
// full ILP); validity gates only the register-side accumulate. Quad lanes own
// the SAME node at 4 tick-groups: gather addrs identical (coalescer merges),
// x reads are 64 consecutive bytes. One barrier per block (store staging).

__device__ __forceinline__ void upd(float& mx, float& den, float& p,
                                    const float e, const float pj) {
    const float dif = e - mx;
    const float ex = __expf(-fabsf(dif));
    const bool g = dif > 0.f;
    const float scale = g ? ex : 1.f;
    const float w = g ? 1.f : ex;
    mx = g ? e : mx;
    den = fmaf(den, scale, w);
    p = fmaf(p, scale, w * pj);
}

__device__ __forceinline__ void edge_proc(const bool valid, const float4 cs,
                                          const float4 a4, const float4 b4,
                                          const float sA1, const float sB1,
                                          const float pA1, const float pB1,
                                          const float* tp, const float* dm,
                                          float* mx, float* den, float* pa) {
    const float a[4] = {a4.x, a4.y, a4.z, a4.w};
    const float b[4] = {b4.x, b4.y, b4.z, b4.w};
#pragma unroll
    for (int k = 0; k < TG; k++) {
        // dm[k] already contains dst-projection + tk*sT (src tick term)
        float e = cs.x + a[k] * sA1 + b[k] * sB1 + dm[k];
        e = fmaxf(e, 0.2f * e);
        const float pv = cs.y + a[k] * pA1 + b[k] * pB1 + tp[k];
        if (valid) upd(mx[k], den[k], pa[k], e, pv);
    }
}

__global__ __launch_bounds__(256, 8) void k_gat(
        const float* __restrict__ x,
        const float4* __restrict__ c4,
        const int* __restrict__ counts,
        const int* __restrict__ bucket,
        const float* __restrict__ Wg,
        const float* __restrict__ as_,
        const float* __restrict__ ad_,
        const float* __restrict__ Wm,
        const float* __restrict__ bm,
        float* __restrict__ out) {
    const int lid = blockIdx.x;
    const int tgb = lid & 7;            // tick chunk 0..7 (16 ticks each)
    const int nb  = lid >> 3;           // node window 0..NBLKN-1
    const int bbase = nb * BNODE;
    const int tid = threadIdx.x;

    const int nq  = tid >> 2;           // node slot 0..63
    const int tgl = tid & 3;            // tick lane 0..3
    const int tg  = tgb * 4 + tgl;      // tick group 0..31
    const int n   = bbase + nq;
    const bool act = n < NCROSS;
    const int nc = act ? n : 0;         // clamped (tail block)

    __shared__ float lres[TGB][BNODE + 1];   // +1 pad: kills 4-way write conflict

    // head loads: all independent, issue immediately (quad-merged addresses)
    const int deg = act ? min(counts[nc], CAP) : 0;
    const float4 cc = c4[nc];
    const int* bkt = bucket + (size_t)nc * CAP;

    // 9 global projection scalars (uniform -> scalar loads, overlap with above)
    float sA1 = 0, dA1 = 0, pA1 = 0, sB1 = 0, dB1 = 0, pB1 = 0,
          sT = 0, dT = 0, pT = 0;
#pragma unroll
    for (int c = 0; c < 4; c++) {
        const float va = as_[c], vd = ad_[c], vm = Wm[c];
        const float w0 = Wg[c], w5 = Wg[5 * 4 + c], w12 = Wg[12 * 4 + c];
        sA1 = fmaf(w0, va, sA1);  dA1 = fmaf(w0, vd, dA1);  pA1 = fmaf(w0, vm, pA1);
        sB1 = fmaf(w5, va, sB1);  dB1 = fmaf(w5, vd, dB1);  pB1 = fmaf(w5, vm, pB1);
        sT  = fmaf(w12, va, sT);  dT  = fmaf(w12, vd, dT);  pT  = fmaf(w12, vm, pT);
    }

    const int cab = __float_as_int(cc.w);
    const float4 a4 = *(const float4*)(x + (cab & 0xffff) * T_TICKS + tg * TG);
    const float4 b4 = *(const float4*)(x + (cab >> 16) * T_TICKS + tg * TG);
    const float a[4] = {a4.x, a4.y, a4.z, a4.w};
    const float b[4] = {b4.x, b4.y, b4.z, b4.w};

    float dm[TG], tp[TG];
#pragma unroll
    for (int k = 0; k < TG; k++) {
        const float tk = (float)(tg * TG + k);
        dm[k] = cc.z + a[k] * dA1 + b[k] * dB1 + tk * dT + tk * sT;
        tp[k] = tk * pT;
    }
    float mx[TG], den[TG], pa[TG];
#pragma unroll
    for (int k = 0; k < TG; k++) { mx[k] = -INFINITY; den[k] = 0.f; pa[k] = 0.f; }

    for (int j = 0; j < deg; j += 4) {
        const int4 bb = *(const int4*)(bkt + j);
        const int m = deg - j;
        // clamp: loads unconditional & in-bounds even on poison slots
        const int s0 = min(max(bb.x, 0), NCROSS - 1);
        const int s1 = min(max(bb.y, 0), NCROSS - 1);
        const int s2 = min(max(bb.z, 0), NCROSS - 1);
        const int s3 = min(max(bb.w, 0), NCROSS - 1);
        const float4 cs0 = c4[s0];
        const float4 cs1 = c4[s1];
        const float4 cs2 = c4[s2];
        const float4 cs3 = c4[s3];
        const int i0 = __float_as_int(cs0.w);
        const int i1 = __float_as_int(cs1.w);
        const int i2 = __float_as_int(cs2.w);
        const int i3 = __float_as_int(cs3.w);
        const float4 xa0 = *(const float4*)(x + (i0 & 0xffff) * T_TICKS + tg * TG);
        const float4 xb0 = *(const float4*)(x + (i0 >> 16) * T_TICKS + tg * TG);
        const float4 xa1 = *(const float4*)(x + (i1 & 0xffff) * T_TICKS + tg * TG);
        const float4 xb1 = *(const float4*)(x + (i1 >> 16) * T_TICKS + tg * TG);
        const float4 xa2 = *(const float4*)(x + (i2 & 0xffff) * T_TICKS + tg * TG);
        const float4 xb2 = *(const float4*)(x + (i2 >> 16) * T_TICKS + tg * TG);
        const float4 xa3 = *(const float4*)(x + (i3 & 0xffff) * T_TICKS + tg * TG);
        const float4 xb3 = *(const float4*)(x + (i3 >> 16) * T_TICKS + tg * TG);
        edge_proc(true,  cs0, xa0, xb0, sA1, sB1, pA1, pB1, tp, dm, mx, den, pa);
        edge_proc(m > 1, cs1, xa1, xb1, sA1, sB1, pA1, pB1, tp, dm, mx, den, pa);
        edge_proc(m > 2, cs2, xa2, xb2, sA1, sB1, pA1, pB1, tp, dm, mx, den, pa);
        edge_proc(m > 3, cs3, xa3, xb3, sA1, sB1, pA1, pB1, tp, dm, mx, den, pa);
    }

    if (act) {
        const float bb2 = bm[0];
#pragma unroll
        for (int k = 0; k < TG; k++) {
            const float logit = pa[k] / (den[k] + 1e-9f) + bb2;
            lres[tgl * 4 + k][nq] = 1.f / (1.f + __expf(-logit));
        }
    }
    __syncthreads();

    // coalesced store: wave w writes rows 4w..4w+3, lane = node column
    {
        const int col = tid & 63;
        const int wv  = tid >> 6;
        if (bbase + col < NCROSS) {
#pragma unroll
            for (int rr = 0; rr < 4; rr++) {
                const int row = wv * 4 + rr;
                out[(size_t)(tgb * TGB + row) * NCROSS + bbase + col] =
                    lres[row][col];
            }
        }
    }
}

// ---------------- launch ----------------

extern "C" void kernel_launch(void* const* d_in, const int* in_sizes, int n_in,
                              void* d_out, int out_size, void* d_ws, size_t ws_size,
                              hipStream_t stream) {
    const float* x   = (const float*)d_in[0];
    const int* c0  = (const int*)d_in[1];
    const int* c1  = (const int*)d_in[2];
    const int* c2  = (const int*)d_in[3];
    const int* g01 = (const int*)d_in[4];
    const int* g12 = (const int*)d_in[5];
    const int* g20 = (const int*)d_in[6];
    const float* r01 = (const float*)d_in[7];
    const float* r12 = (const float*)d_in[8];
    const float* r20 = (const float*)d_in[9];
    const int* edges = (const int*)d_in[10];          // [2, E]
    const float* Wg  = (const float*)d_in[11];
    const float* as_ = (const float*)d_in[12];
    const float* ad_ = (const float*)d_in[13];
    const float* bg  = (const float*)d_in[14];
    const float* Wm  = (const float*)d_in[15];
    const float* bm  = (const float*)d_in[16];
    float* out = (float*)d_out;

    const int* e_src = edges;
    const int* e_dst = edges + E_EDGES;

    // workspace layout (~4.5 MB total)
    char* ws = (char*)d_ws;
    size_t off = 0;
    int* counts = (int*)(ws + off); off += NCROSS * sizeof(int);
    off = (off + 255) & ~(size_t)255;
    int* bucket = (int*)(ws + off); off += (size_t)NCROSS * CAP * sizeof(int);  // 3.84 MB
    off = (off + 255) & ~(size_t)255;
    float4* c4 = (float4*)(ws + off); off += (size_t)NCROSS * sizeof(float4);   // 480 KB
    (void)ws_size; (void)n_in; (void)in_sizes; (void)out_size;

    hipMemsetAsync(counts, 0, NCROSS * sizeof(int), stream);

    k_prep<<<(PREP_ITEMS + 255) / 256, 256, 0, stream>>>(
        x, c0, c1, c2, g01, g12, g20, r01, r12, r20, Wg, bg, as_, ad_, Wm,
        e_src, e_dst, counts, bucket, c4);

    k_gat<<<NBLKN * NCHUNK, 256, 0, stream>>>(x, c4, counts, bucket,
                                              Wg, as_, ad_, Wm, bm, out);
}

// Round 5
// 133.641 us; speedup vs baseline: 1.1786x; 1.1786x over previous
//
#include <hip/hip_runtime.h>

// Problem constants (match reference)
#define T_TICKS 128
#define NCH     1536
#define NCPAIR  10000
#define NCROSS  30000
#define E_EDGES 120000
#define TG      4               // ticks per thread
#define TGB     16              // ticks per block (4 tick-lanes x TG)
#define NCHUNK  (T_TICKS / TGB) // 8 tick chunks
#define CAP     32              // bucket capacity (deg ~ Poisson(4))
#define BNODE   64              // nodes per k_gat block
#define NBLKN   ((NCROSS + BNODE - 1) / BNODE)  // 469
#define PREP_ITEMS (NCROSS + E_EDGES)

// ---------------- prep: per-node tick-static scalars + edge scatter ----------
// h(t)·a = hB + x[chA][t]*hA1 + x[chB][t]*hB1 + t*hT with hA1/hB1/hT global
// scalars. Per node: c4 = {sB, pB, dB, chA|chB<<16} -- ONE 16-B record serves
// both "own" and "neighbor" roles. Bucket node-major [n][CAP] (128-B rows).

__global__ void k_prep(const float* __restrict__ x,
                       const int* __restrict__ c0, const int* __restrict__ c1,
                       const int* __restrict__ c2,
                       const int* __restrict__ g01, const int* __restrict__ g12,
                       const int* __restrict__ g20,
                       const float* __restrict__ r01,
                       const float* __restrict__ r12,
                       const float* __restrict__ r20,
                       const float* __restrict__ Wg,
                       const float* __restrict__ bg,
                       const float* __restrict__ as_,
                       const float* __restrict__ ad_,
                       const float* __restrict__ Wm,
                       const int* __restrict__ e_src,
                       const int* __restrict__ e_dst,
                       int* __restrict__ counts,
                       int* __restrict__ bucket,
                       float4* __restrict__ c4) {
    const int gid = blockIdx.x * 256 + threadIdx.x;
    if (gid < NCROSS) {
        const int n = gid;
        int iA, iB, m;
        float pA, pB;
        const int* cA;
        const int* cB;
        const float* ray;
        if (n < NCPAIR) {
            m = n; cA = c0; cB = c1; pA = 0.f; pB = 1.f; ray = r01;
            iA = g01[2 * m]; iB = g01[2 * m + 1];
        } else if (n < 2 * NCPAIR) {
            m = n - NCPAIR; cA = c1; cB = c2; pA = 1.f; pB = 2.f; ray = r12;
            iA = g12[2 * m]; iB = g12[2 * m + 1];
        } else {
            m = n - 2 * NCPAIR; cA = c2; cB = c0; pA = 2.f; pB = 0.f; ray = r20;
            iA = g20[2 * m]; iB = g20[2 * m + 1];
        }
        const int chA = cA[iA];
        const int chB = cB[iB];
        const float rx = ray[2 * m];
        const float ry = ray[2 * m + 1];

        float base[4];
#pragma unroll
        for (int c = 0; c < 4; c++) {
            base[c] = bg[c]
                    + (float)iA  * Wg[1 * 4 + c] + (float)chA * Wg[2 * 4 + c]
                    + pA         * Wg[4 * 4 + c]
                    + (float)iB  * Wg[6 * 4 + c] + (float)chB * Wg[7 * 4 + c]
                    + pB         * Wg[9 * 4 + c]
                    + rx         * Wg[10 * 4 + c] + ry * Wg[11 * 4 + c];
        }
        float sB = 0.f, dB = 0.f, pBs = 0.f;
#pragma unroll
        for (int c = 0; c < 4; c++) {
            sB  = fmaf(base[c], as_[c], sB);
            dB  = fmaf(base[c], ad_[c], dB);
            pBs = fmaf(base[c], Wm[c], pBs);
        }
        c4[n] = make_float4(sB, pBs, dB, __int_as_float(chA | (chB << 16)));
    } else if (gid < PREP_ITEMS) {
        const int i = gid - NCROSS;
        const int s = e_src[i];
        const int d = e_dst[i];
        const int slot = atomicAdd(&counts[d], 1);
        if (slot < CAP) bucket[(size_t)d * CAP + slot] = s;
    }
}

// ---------------- GAT aggregation + MLP + sigmoid ----------------------------
// Block = 64 nodes x 4 tick-lanes, no degree sort: counts[n], c4[n] and the
// bucket int4 row are address-independent -> all issue at cycle 0. Neighbor
// indices clamped to [0,NCROSS) so every load is unconditional (poison-safe,
// full ILP); validity gates only the register-side accumulate. Quad lanes own
// the SAME node at 4 tick-groups: gather addrs identical (coalescer merges),
// x reads are 64 consecutive bytes. One barrier per block (store staging).
// __launch_bounds__(256,5): VGPR cap 102 >= ~90 natural demand -> NO SPILLS
// (the (256,8)=64-cap variant spilled ~100 MB of scratch traffic: R4 lesson).

__device__ __forceinline__ void upd(float& mx, float& den, float& p,
                                    const float e, const float pj) {
    const float dif = e - mx;
    const float ex = __expf(-fabsf(dif));
    const bool g = dif > 0.f;
    const float scale = g ? ex : 1.f;
    const float w = g ? 1.f : ex;
    mx = g ? e : mx;
    den = fmaf(den, scale, w);
    p = fmaf(p, scale, w * pj);
}

__device__ __forceinline__ void edge_proc(const bool valid, const float4 cs,
                                          const float4 a4, const float4 b4,
                                          const float sA1, const float sB1,
                                          const float pA1, const float pB1,
                                          const float* tp, const float* dm,
                                          float* mx, float* den, float* pa) {
    const float a[4] = {a4.x, a4.y, a4.z, a4.w};
    const float b[4] = {b4.x, b4.y, b4.z, b4.w};
#pragma unroll
    for (int k = 0; k < TG; k++) {
        // dm[k] already contains dst-projection + tk*sT (src tick term)
        float e = cs.x + a[k] * sA1 + b[k] * sB1 + dm[k];
        e = fmaxf(e, 0.2f * e);
        const float pv = cs.y + a[k] * pA1 + b[k] * pB1 + tp[k];
        if (valid) upd(mx[k], den[k], pa[k], e, pv);
    }
}

__global__ __launch_bounds__(256, 5) void k_gat(
        const float* __restrict__ x,
        const float4* __restrict__ c4,
        const int* __restrict__ counts,
        const int* __restrict__ bucket,
        const float* __restrict__ Wg,
        const float* __restrict__ as_,
        const float* __restrict__ ad_,
        const float* __restrict__ Wm,
        const float* __restrict__ bm,
        float* __restrict__ out) {
    const int lid = blockIdx.x;
    const int tgb = lid & 7;            // tick chunk 0..7 (16 ticks each)
    const int nb  = lid >> 3;           // node window 0..NBLKN-1
    const int bbase = nb * BNODE;
    const int tid = threadIdx.x;

    const int nq  = tid >> 2;           // node slot 0..63
    const int tgl = tid & 3;            // tick lane 0..3
    const int tg  = tgb * 4 + tgl;      // tick group 0..31
    const int n   = bbase + nq;
    const bool act = n < NCROSS;
    const int nc = act ? n : 0;         // clamped (tail block)

    // stride 68: write pattern (row=tgl*4+k, col=nq) lands 2-way on banks
    // (free on CDNA4); the 65-stride variant was 4-way.
    __shared__ float lres[TGB][BNODE + 4];

    // head loads: all independent, issue immediately (quad-merged addresses)
    const int deg = act ? min(counts[nc], CAP) : 0;
    const float4 cc = c4[nc];
    const int* bkt = bucket + (size_t)nc * CAP;

    // 9 global projection scalars (uniform -> scalar loads, overlap with above)
    float sA1 = 0, dA1 = 0, pA1 = 0, sB1 = 0, dB1 = 0, pB1 = 0,
          sT = 0, dT = 0, pT = 0;
#pragma unroll
    for (int c = 0; c < 4; c++) {
        const float va = as_[c], vd = ad_[c], vm = Wm[c];
        const float w0 = Wg[c], w5 = Wg[5 * 4 + c], w12 = Wg[12 * 4 + c];
        sA1 = fmaf(w0, va, sA1);  dA1 = fmaf(w0, vd, dA1);  pA1 = fmaf(w0, vm, pA1);
        sB1 = fmaf(w5, va, sB1);  dB1 = fmaf(w5, vd, dB1);  pB1 = fmaf(w5, vm, pB1);
        sT  = fmaf(w12, va, sT);  dT  = fmaf(w12, vd, dT);  pT  = fmaf(w12, vm, pT);
    }

    const int cab = __float_as_int(cc.w);
    const float4 a4 = *(const float4*)(x + (cab & 0xffff) * T_TICKS + tg * TG);
    const float4 b4 = *(const float4*)(x + (cab >> 16) * T_TICKS + tg * TG);
    const float a[4] = {a4.x, a4.y, a4.z, a4.w};
    const float b[4] = {b4.x, b4.y, b4.z, b4.w};

    float dm[TG], tp[TG];
#pragma unroll
    for (int k = 0; k < TG; k++) {
        const float tk = (float)(tg * TG + k);
        dm[k] = cc.z + a[k] * dA1 + b[k] * dB1 + tk * dT + tk * sT;
        tp[k] = tk * pT;
    }
    float mx[TG], den[TG], pa[TG];
#pragma unroll
    for (int k = 0; k < TG; k++) { mx[k] = -INFINITY; den[k] = 0.f; pa[k] = 0.f; }

    for (int j = 0; j < deg; j += 4) {
        const int4 bb = *(const int4*)(bkt + j);
        const int m = deg - j;
        // clamp: loads unconditional & in-bounds even on poison slots
        const int s0 = min(max(bb.x, 0), NCROSS - 1);
        const int s1 = min(max(bb.y, 0), NCROSS - 1);
        const int s2 = min(max(bb.z, 0), NCROSS - 1);
        const int s3 = min(max(bb.w, 0), NCROSS - 1);
        const float4 cs0 = c4[s0];
        const float4 cs1 = c4[s1];
        const float4 cs2 = c4[s2];
        const float4 cs3 = c4[s3];
        const int i0 = __float_as_int(cs0.w);
        const int i1 = __float_as_int(cs1.w);
        const int i2 = __float_as_int(cs2.w);
        const int i3 = __float_as_int(cs3.w);
        const float4 xa0 = *(const float4*)(x + (i0 & 0xffff) * T_TICKS + tg * TG);
        const float4 xb0 = *(const float4*)(x + (i0 >> 16) * T_TICKS + tg * TG);
        const float4 xa1 = *(const float4*)(x + (i1 & 0xffff) * T_TICKS + tg * TG);
        const float4 xb1 = *(const float4*)(x + (i1 >> 16) * T_TICKS + tg * TG);
        const float4 xa2 = *(const float4*)(x + (i2 & 0xffff) * T_TICKS + tg * TG);
        const float4 xb2 = *(const float4*)(x + (i2 >> 16) * T_TICKS + tg * TG);
        const float4 xa3 = *(const float4*)(x + (i3 & 0xffff) * T_TICKS + tg * TG);
        const float4 xb3 = *(const float4*)(x + (i3 >> 16) * T_TICKS + tg * TG);
        edge_proc(true,  cs0, xa0, xb0, sA1, sB1, pA1, pB1, tp, dm, mx, den, pa);
        edge_proc(m > 1, cs1, xa1, xb1, sA1, sB1, pA1, pB1, tp, dm, mx, den, pa);
        edge_proc(m > 2, cs2, xa2, xb2, sA1, sB1, pA1, pB1, tp, dm, mx, den, pa);
        edge_proc(m > 3, cs3, xa3, xb3, sA1, sB1, pA1, pB1, tp, dm, mx, den, pa);
    }

    if (act) {
        const float bb2 = bm[0];
#pragma unroll
        for (int k = 0; k < TG; k++) {
            const float logit = pa[k] / (den[k] + 1e-9f) + bb2;
            lres[tgl * 4 + k][nq] = 1.f / (1.f + __expf(-logit));
        }
    }
    __syncthreads();

    // coalesced store: wave w writes rows 4w..4w+3, lane = node column
    {
        const int col = tid & 63;
        const int wv  = tid >> 6;
        if (bbase + col < NCROSS) {
#pragma unroll
            for (int rr = 0; rr < 4; rr++) {
                const int row = wv * 4 + rr;
                out[(size_t)(tgb * TGB + row) * NCROSS + bbase + col] =
                    lres[row][col];
            }
        }
    }
}

// ---------------- launch ----------------

extern "C" void kernel_launch(void* const* d_in, const int* in_sizes, int n_in,
                              void* d_out, int out_size, void* d_ws, size_t ws_size,
                              hipStream_t stream) {
    const float* x   = (const float*)d_in[0];
    const int* c0  = (const int*)d_in[1];
    const int* c1  = (const int*)d_in[2];
    const int* c2  = (const int*)d_in[3];
    const int* g01 = (const int*)d_in[4];
    const int* g12 = (const int*)d_in[5];
    const int* g20 = (const int*)d_in[6];
    const float* r01 = (const float*)d_in[7];
    const float* r12 = (const float*)d_in[8];
    const float* r20 = (const float*)d_in[9];
    const int* edges = (const int*)d_in[10];          // [2, E]
    const float* Wg  = (const float*)d_in[11];
    const float* as_ = (const float*)d_in[12];
    const float* ad_ = (const float*)d_in[13];
    const float* bg  = (const float*)d_in[14];
    const float* Wm  = (const float*)d_in[15];
    const float* bm  = (const float*)d_in[16];
    float* out = (float*)d_out;

    const int* e_src = edges;
    const int* e_dst = edges + E_EDGES;

    // workspace layout (~4.5 MB total)
    char* ws = (char*)d_ws;
    size_t off = 0;
    int* counts = (int*)(ws + off); off += NCROSS * sizeof(int);
    off = (off + 255) & ~(size_t)255;
    int* bucket = (int*)(ws + off); off += (size_t)NCROSS * CAP * sizeof(int);  // 3.84 MB
    off = (off + 255) & ~(size_t)255;
    float4* c4 = (float4*)(ws + off); off += (size_t)NCROSS * sizeof(float4);   // 480 KB
    (void)ws_size; (void)n_in; (void)in_sizes; (void)out_size;

    hipMemsetAsync(counts, 0, NCROSS * sizeof(int), stream);

    k_prep<<<(PREP_ITEMS + 255) / 256, 256, 0, stream>>>(
        x, c0, c1, c2, g01, g12, g20, r01, r12, r20, Wg, bg, as_, ad_, Wm,
        e_src, e_dst, counts, bucket, c4);

    k_gat<<<NBLKN * NCHUNK, 256, 0, stream>>>(x, c4, counts, bucket,
                                              Wg, as_, ad_, Wm, bm, out);
}

// Round 6
// 125.712 us; speedup vs baseline: 1.2529x; 1.0631x over previous
//
#include <hip/hip_runtime.h>

// Problem constants (match reference)
#define T_TICKS 128
#define NCH     1536
#define NCPAIR  10000
#define NCROSS  30000
#define E_EDGES 120000
#define TG      4               // ticks per thread
#define TGB     64              // ticks per block (16 tick-lanes x TG)
#define NCHUNK  (T_TICKS / TGB) // 2 tick chunks
#define CAP     32              // bucket capacity (deg ~ Poisson(4))
#define BNODE   16              // nodes per k_gat block (30000 % 16 == 0)
#define NBLKN   (NCROSS / BNODE)               // 1875
#define PREP_ITEMS (NCROSS + E_EDGES)

// ---------------- prep: per-node tick-static scalars + edge scatter ----------
// h(t)·a = hB + x[chA][t]*hA1 + x[chB][t]*hB1 + t*hT with hA1/hB1/hT global
// scalars. Per node: c4 = {sB, pB, dB, chA|chB<<16} -- ONE 16-B record serves
// both "own" and "neighbor" roles. Bucket node-major [n][CAP] (128-B rows).

__global__ void k_prep(const float* __restrict__ x,
                       const int* __restrict__ c0, const int* __restrict__ c1,
                       const int* __restrict__ c2,
                       const int* __restrict__ g01, const int* __restrict__ g12,
                       const int* __restrict__ g20,
                       const float* __restrict__ r01,
                       const float* __restrict__ r12,
                       const float* __restrict__ r20,
                       const float* __restrict__ Wg,
                       const float* __restrict__ bg,
                       const float* __restrict__ as_,
                       const float* __restrict__ ad_,
                       const float* __restrict__ Wm,
                       const int* __restrict__ e_src,
                       const int* __restrict__ e_dst,
                       int* __restrict__ counts,
                       int* __restrict__ bucket,
                       float4* __restrict__ c4) {
    const int gid = blockIdx.x * 256 + threadIdx.x;
    if (gid < NCROSS) {
        const int n = gid;
        int iA, iB, m;
        float pA, pB;
        const int* cA;
        const int* cB;
        const float* ray;
        if (n < NCPAIR) {
            m = n; cA = c0; cB = c1; pA = 0.f; pB = 1.f; ray = r01;
            iA = g01[2 * m]; iB = g01[2 * m + 1];
        } else if (n < 2 * NCPAIR) {
            m = n - NCPAIR; cA = c1; cB = c2; pA = 1.f; pB = 2.f; ray = r12;
            iA = g12[2 * m]; iB = g12[2 * m + 1];
        } else {
            m = n - 2 * NCPAIR; cA = c2; cB = c0; pA = 2.f; pB = 0.f; ray = r20;
            iA = g20[2 * m]; iB = g20[2 * m + 1];
        }
        const int chA = cA[iA];
        const int chB = cB[iB];
        const float rx = ray[2 * m];
        const float ry = ray[2 * m + 1];

        float base[4];
#pragma unroll
        for (int c = 0; c < 4; c++) {
            base[c] = bg[c]
                    + (float)iA  * Wg[1 * 4 + c] + (float)chA * Wg[2 * 4 + c]
                    + pA         * Wg[4 * 4 + c]
                    + (float)iB  * Wg[6 * 4 + c] + (float)chB * Wg[7 * 4 + c]
                    + pB         * Wg[9 * 4 + c]
                    + rx         * Wg[10 * 4 + c] + ry * Wg[11 * 4 + c];
        }
        float sB = 0.f, dB = 0.f, pBs = 0.f;
#pragma unroll
        for (int c = 0; c < 4; c++) {
            sB  = fmaf(base[c], as_[c], sB);
            dB  = fmaf(base[c], ad_[c], dB);
            pBs = fmaf(base[c], Wm[c], pBs);
        }
        c4[n] = make_float4(sB, pBs, dB, __int_as_float(chA | (chB << 16)));
    } else if (gid < PREP_ITEMS) {
        const int i = gid - NCROSS;
        const int s = e_src[i];
        const int d = e_dst[i];
        const int slot = atomicAdd(&counts[d], 1);
        if (slot < CAP) bucket[(size_t)d * CAP + slot] = s;
    }
}

// ---------------- GAT aggregation + MLP + sigmoid ----------------------------
// Block = 16 nodes x 16 tick-lanes (TGB=64 ticks/block, 2 chunks). The 16
// lanes of a node-slot share ALL per-node/per-edge gather addresses
// (counts/c4/bucket: coalescer merges to one line) and their x reads are 256
// consecutive bytes. vs the 4-lane/8-chunk layout this cuts gather
// multiplicity 8x -> 2x with an IDENTICAL per-thread register body (TG=4,
// ~95 VGPR, (256,5): no spills -- R4 lesson). No degree sort: counts[n],
// c4[n], bucket row are address-independent -> issue at cycle 0; neighbor
// indices clamped so loads are unconditional (poison-safe), validity gates
// only the register-side accumulate. One barrier per block (store staging).

__device__ __forceinline__ void upd(float& mx, float& den, float& p,
                                    const float e, const float pj) {
    const float dif = e - mx;
    const float ex = __expf(-fabsf(dif));
    const bool g = dif > 0.f;
    const float scale = g ? ex : 1.f;
    const float w = g ? 1.f : ex;
    mx = g ? e : mx;
    den = fmaf(den, scale, w);
    p = fmaf(p, scale, w * pj);
}

__device__ __forceinline__ void edge_proc(const bool valid, const float4 cs,
                                          const float4 a4, const float4 b4,
                                          const float sA1, const float sB1,
                                          const float pA1, const float pB1,
                                          const float* tp, const float* dm,
                                          float* mx, float* den, float* pa) {
    const float a[4] = {a4.x, a4.y, a4.z, a4.w};
    const float b[4] = {b4.x, b4.y, b4.z, b4.w};
#pragma unroll
    for (int k = 0; k < TG; k++) {
        // dm[k] already contains dst-projection + tk*sT (src tick term)
        float e = cs.x + a[k] * sA1 + b[k] * sB1 + dm[k];
        e = fmaxf(e, 0.2f * e);
        const float pv = cs.y + a[k] * pA1 + b[k] * pB1 + tp[k];
        if (valid) upd(mx[k], den[k], pa[k], e, pv);
    }
}

__global__ __launch_bounds__(256, 5) void k_gat(
        const float* __restrict__ x,
        const float4* __restrict__ c4,
        const int* __restrict__ counts,
        const int* __restrict__ bucket,
        const float* __restrict__ Wg,
        const float* __restrict__ as_,
        const float* __restrict__ ad_,
        const float* __restrict__ Wm,
        const float* __restrict__ bm,
        float* __restrict__ out) {
    const int lid = blockIdx.x;
    const int tgb = lid & 1;            // tick chunk 0..1 (64 ticks each)
    const int nb  = lid >> 1;           // node window 0..NBLKN-1
    const int bbase = nb * BNODE;
    const int tid = threadIdx.x;

    const int nq  = tid >> 4;           // node slot 0..15
    const int tgl = tid & 15;           // tick lane 0..15
    const int tg  = tgb * 16 + tgl;     // tick group 0..31
    const int n   = bbase + nq;         // always < NCROSS (30000 % 16 == 0)

    // stride 19: writer pattern (76*tgl + 19k + nq) is 2-way on banks (free)
    __shared__ float lres[TGB][19];

    // head loads: all independent, issue immediately (lane-merged addresses)
    const int deg = min(counts[n], CAP);
    const float4 cc = c4[n];
    const int* bkt = bucket + (size_t)n * CAP;

    // 9 global projection scalars (uniform -> scalar loads, overlap with above)
    float sA1 = 0, dA1 = 0, pA1 = 0, sB1 = 0, dB1 = 0, pB1 = 0,
          sT = 0, dT = 0, pT = 0;
#pragma unroll
    for (int c = 0; c < 4; c++) {
        const float va = as_[c], vd = ad_[c], vm = Wm[c];
        const float w0 = Wg[c], w5 = Wg[5 * 4 + c], w12 = Wg[12 * 4 + c];
        sA1 = fmaf(w0, va, sA1);  dA1 = fmaf(w0, vd, dA1);  pA1 = fmaf(w0, vm, pA1);
        sB1 = fmaf(w5, va, sB1);  dB1 = fmaf(w5, vd, dB1);  pB1 = fmaf(w5, vm, pB1);
        sT  = fmaf(w12, va, sT);  dT  = fmaf(w12, vd, dT);  pT  = fmaf(w12, vm, pT);
    }

    const int cab = __float_as_int(cc.w);
    const float4 a4 = *(const float4*)(x + (cab & 0xffff) * T_TICKS + tg * TG);
    const float4 b4 = *(const float4*)(x + (cab >> 16) * T_TICKS + tg * TG);
    const float a[4] = {a4.x, a4.y, a4.z, a4.w};
    const float b[4] = {b4.x, b4.y, b4.z, b4.w};

    float dm[TG], tp[TG];
#pragma unroll
    for (int k = 0; k < TG; k++) {
        const float tk = (float)(tg * TG + k);
        dm[k] = cc.z + a[k] * dA1 + b[k] * dB1 + tk * dT + tk * sT;
        tp[k] = tk * pT;
    }
    float mx[TG], den[TG], pa[TG];
#pragma unroll
    for (int k = 0; k < TG; k++) { mx[k] = -INFINITY; den[k] = 0.f; pa[k] = 0.f; }

    for (int j = 0; j < deg; j += 4) {
        const int4 bb = *(const int4*)(bkt + j);
        const int m = deg - j;
        // clamp: loads unconditional & in-bounds even on poison slots
        const int s0 = min(max(bb.x, 0), NCROSS - 1);
        const int s1 = min(max(bb.y, 0), NCROSS - 1);
        const int s2 = min(max(bb.z, 0), NCROSS - 1);
        const int s3 = min(max(bb.w, 0), NCROSS - 1);
        const float4 cs0 = c4[s0];
        const float4 cs1 = c4[s1];
        const float4 cs2 = c4[s2];
        const float4 cs3 = c4[s3];
        const int i0 = __float_as_int(cs0.w);
        const int i1 = __float_as_int(cs1.w);
        const int i2 = __float_as_int(cs2.w);
        const int i3 = __float_as_int(cs3.w);
        const float4 xa0 = *(const float4*)(x + (i0 & 0xffff) * T_TICKS + tg * TG);
        const float4 xb0 = *(const float4*)(x + (i0 >> 16) * T_TICKS + tg * TG);
        const float4 xa1 = *(const float4*)(x + (i1 & 0xffff) * T_TICKS + tg * TG);
        const float4 xb1 = *(const float4*)(x + (i1 >> 16) * T_TICKS + tg * TG);
        const float4 xa2 = *(const float4*)(x + (i2 & 0xffff) * T_TICKS + tg * TG);
        const float4 xb2 = *(const float4*)(x + (i2 >> 16) * T_TICKS + tg * TG);
        const float4 xa3 = *(const float4*)(x + (i3 & 0xffff) * T_TICKS + tg * TG);
        const float4 xb3 = *(const float4*)(x + (i3 >> 16) * T_TICKS + tg * TG);
        edge_proc(true,  cs0, xa0, xb0, sA1, sB1, pA1, pB1, tp, dm, mx, den, pa);
        edge_proc(m > 1, cs1, xa1, xb1, sA1, sB1, pA1, pB1, tp, dm, mx, den, pa);
        edge_proc(m > 2, cs2, xa2, xb2, sA1, sB1, pA1, pB1, tp, dm, mx, den, pa);
        edge_proc(m > 3, cs3, xa3, xb3, sA1, sB1, pA1, pB1, tp, dm, mx, den, pa);
    }

    {
        const float bb2 = bm[0];
#pragma unroll
        for (int k = 0; k < TG; k++) {
            const float logit = pa[k] / (den[k] + 1e-9f) + bb2;
            lres[tgl * 4 + k][nq] = 1.f / (1.f + __expf(-logit));
        }
    }
    __syncthreads();

    // coalesced store: 64 rows x 16 cols; per instruction a wave covers
    // 4 rows x 16 cols = 4 contiguous 64-B segments.
    {
        const int col = tid & 15;
        const int rb  = (tid >> 4) * 4;
#pragma unroll
        for (int rr = 0; rr < 4; rr++) {
            const int row = rb + rr;
            out[(size_t)(tgb * TGB + row) * NCROSS + bbase + col] =
                lres[row][col];
        }
    }
}

// ---------------- launch ----------------

extern "C" void kernel_launch(void* const* d_in, const int* in_sizes, int n_in,
                              void* d_out, int out_size, void* d_ws, size_t ws_size,
                              hipStream_t stream) {
    const float* x   = (const float*)d_in[0];
    const int* c0  = (const int*)d_in[1];
    const int* c1  = (const int*)d_in[2];
    const int* c2  = (const int*)d_in[3];
    const int* g01 = (const int*)d_in[4];
    const int* g12 = (const int*)d_in[5];
    const int* g20 = (const int*)d_in[6];
    const float* r01 = (const float*)d_in[7];
    const float* r12 = (const float*)d_in[8];
    const float* r20 = (const float*)d_in[9];
    const int* edges = (const int*)d_in[10];          // [2, E]
    const float* Wg  = (const float*)d_in[11];
    const float* as_ = (const float*)d_in[12];
    const float* ad_ = (const float*)d_in[13];
    const float* bg  = (const float*)d_in[14];
    const float* Wm  = (const float*)d_in[15];
    const float* bm  = (const float*)d_in[16];
    float* out = (float*)d_out;

    const int* e_src = edges;
    const int* e_dst = edges + E_EDGES;

    // workspace layout (~4.5 MB total)
    char* ws = (char*)d_ws;
    size_t off = 0;
    int* counts = (int*)(ws + off); off += NCROSS * sizeof(int);
    off = (off + 255) & ~(size_t)255;
    int* bucket = (int*)(ws + off); off += (size_t)NCROSS * CAP * sizeof(int);  // 3.84 MB
    off = (off + 255) & ~(size_t)255;
    float4* c4 = (float4*)(ws + off); off += (size_t)NCROSS * sizeof(float4);   // 480 KB
    (void)ws_size; (void)n_in; (void)in_sizes; (void)out_size;

    hipMemsetAsync(counts, 0, NCROSS * sizeof(int), stream);

    k_prep<<<(PREP_ITEMS + 255) / 256, 256, 0, stream>>>(
        x, c0, c1, c2, g01, g12, g20, r01, r12, r20, Wg, bg, as_, ad_, Wm,
        e_src, e_dst, counts, bucket, c4);

    k_gat<<<NBLKN * NCHUNK, 256, 0, stream>>>(x, c4, counts, bucket,
                                              Wg, as_, ad_, Wm, bm, out);
}

// Round 7
// 125.082 us; speedup vs baseline: 1.2592x; 1.0050x over previous
//
#include <hip/hip_runtime.h>

// Problem constants (match reference)
#define T_TICKS 128
#define NCH     1536
#define NCPAIR  10000
#define NCROSS  30000
#define E_EDGES 120000
#define TG      4               // ticks per thread
#define CAP     32              // bucket capacity (deg ~ Poisson(4))
#define BNODE   16              // nodes per k_gat block (30000 % 16 == 0)
#define NBLKN   (NCROSS / BNODE)               // 1875
#define PREP_ITEMS (NCROSS + E_EDGES)

// ---------------- prep: per-node tick-static scalars + edge scatter ----------
// h(t)·a = hB + x[chA][t]*hA1 + x[chB][t]*hB1 + t*hT with hA1/hB1/hT global
// scalars. Per node: c4 = {sB, pB, dB, chA|chB<<16} -- ONE 16-B record serves
// both "own" and "neighbor" roles. Bucket node-major [n][CAP] (128-B rows).

__global__ void k_prep(const float* __restrict__ x,
                       const int* __restrict__ c0, const int* __restrict__ c1,
                       const int* __restrict__ c2,
                       const int* __restrict__ g01, const int* __restrict__ g12,
                       const int* __restrict__ g20,
                       const float* __restrict__ r01,
                       const float* __restrict__ r12,
                       const float* __restrict__ r20,
                       const float* __restrict__ Wg,
                       const float* __restrict__ bg,
                       const float* __restrict__ as_,
                       const float* __restrict__ ad_,
                       const float* __restrict__ Wm,
                       const int* __restrict__ e_src,
                       const int* __restrict__ e_dst,
                       int* __restrict__ counts,
                       int* __restrict__ bucket,
                       float4* __restrict__ c4) {
    const int gid = blockIdx.x * 256 + threadIdx.x;
    if (gid < NCROSS) {
        const int n = gid;
        int iA, iB, m;
        float pA, pB;
        const int* cA;
        const int* cB;
        const float* ray;
        if (n < NCPAIR) {
            m = n; cA = c0; cB = c1; pA = 0.f; pB = 1.f; ray = r01;
            iA = g01[2 * m]; iB = g01[2 * m + 1];
        } else if (n < 2 * NCPAIR) {
            m = n - NCPAIR; cA = c1; cB = c2; pA = 1.f; pB = 2.f; ray = r12;
            iA = g12[2 * m]; iB = g12[2 * m + 1];
        } else {
            m = n - 2 * NCPAIR; cA = c2; cB = c0; pA = 2.f; pB = 0.f; ray = r20;
            iA = g20[2 * m]; iB = g20[2 * m + 1];
        }
        const int chA = cA[iA];
        const int chB = cB[iB];
        const float rx = ray[2 * m];
        const float ry = ray[2 * m + 1];

        float base[4];
#pragma unroll
        for (int c = 0; c < 4; c++) {
            base[c] = bg[c]
                    + (float)iA  * Wg[1 * 4 + c] + (float)chA * Wg[2 * 4 + c]
                    + pA         * Wg[4 * 4 + c]
                    + (float)iB  * Wg[6 * 4 + c] + (float)chB * Wg[7 * 4 + c]
                    + pB         * Wg[9 * 4 + c]
                    + rx         * Wg[10 * 4 + c] + ry * Wg[11 * 4 + c];
        }
        float sB = 0.f, dB = 0.f, pBs = 0.f;
#pragma unroll
        for (int c = 0; c < 4; c++) {
            sB  = fmaf(base[c], as_[c], sB);
            dB  = fmaf(base[c], ad_[c], dB);
            pBs = fmaf(base[c], Wm[c], pBs);
        }
        c4[n] = make_float4(sB, pBs, dB, __int_as_float(chA | (chB << 16)));
    } else if (gid < PREP_ITEMS) {
        const int i = gid - NCROSS;
        const int s = e_src[i];
        const int d = e_dst[i];
        const int slot = atomicAdd(&counts[d], 1);
        if (slot < CAP) bucket[(size_t)d * CAP + slot] = s;
    }
}

// ---------------- GAT aggregation + MLP + sigmoid ----------------------------
// Block = 16 nodes x 32 tick-lanes (512 thr) covering ALL 128 ticks: gather
// multiplicity is now 1 -- every counts/c4/bucket/neighbor-c4 line is
// requested exactly once, and each per-edge x row (512 B) is ONE fully
// contiguous wave access. Per-thread body identical to R6 (TG=4, ~95 VGPR);
// __launch_bounds__(512,4): VGPR cap 128 >= demand -> NO SPILLS (R4 lesson),
// 2 blocks/CU = 16 waves/CU. No degree sort: counts[n], c4[n], bucket row
// are address-independent -> issue at cycle 0; neighbor indices clamped so
// loads are unconditional (poison-safe), validity gates only the
// register-side accumulate. One barrier per block (store staging).

__device__ __forceinline__ void upd(float& mx, float& den, float& p,
                                    const float e, const float pj) {
    const float dif = e - mx;
    const float ex = __expf(-fabsf(dif));
    const bool g = dif > 0.f;
    const float scale = g ? ex : 1.f;
    const float w = g ? 1.f : ex;
    mx = g ? e : mx;
    den = fmaf(den, scale, w);
    p = fmaf(p, scale, w * pj);
}

__device__ __forceinline__ void edge_proc(const bool valid, const float4 cs,
                                          const float4 a4, const float4 b4,
                                          const float sA1, const float sB1,
                                          const float pA1, const float pB1,
                                          const float* tp, const float* dm,
                                          float* mx, float* den, float* pa) {
    const float a[4] = {a4.x, a4.y, a4.z, a4.w};
    const float b[4] = {b4.x, b4.y, b4.z, b4.w};
#pragma unroll
    for (int k = 0; k < TG; k++) {
        // dm[k] already contains dst-projection + tk*sT (src tick term)
        float e = cs.x + a[k] * sA1 + b[k] * sB1 + dm[k];
        e = fmaxf(e, 0.2f * e);
        const float pv = cs.y + a[k] * pA1 + b[k] * pB1 + tp[k];
        if (valid) upd(mx[k], den[k], pa[k], e, pv);
    }
}

__global__ __launch_bounds__(512, 4) void k_gat(
        const float* __restrict__ x,
        const float4* __restrict__ c4,
        const int* __restrict__ counts,
        const int* __restrict__ bucket,
        const float* __restrict__ Wg,
        const float* __restrict__ as_,
        const float* __restrict__ ad_,
        const float* __restrict__ Wm,
        const float* __restrict__ bm,
        float* __restrict__ out) {
    const int nb  = blockIdx.x;         // node window 0..NBLKN-1
    const int bbase = nb * BNODE;
    const int tid = threadIdx.x;

    const int nq  = tid >> 5;           // node slot 0..15
    const int tgl = tid & 31;           // tick lane = tick group 0..31
    const int tg  = tgl;
    const int n   = bbase + nq;         // always < NCROSS (30000 % 16 == 0)

    __shared__ float lres[T_TICKS][BNODE + 1];   // 8.7 KB staging

    // head loads: all independent, issue immediately (lane-merged addresses)
    const int deg = min(counts[n], CAP);
    const float4 cc = c4[n];
    const int* bkt = bucket + (size_t)n * CAP;

    // 9 global projection scalars (uniform -> scalar loads, overlap with above)
    float sA1 = 0, dA1 = 0, pA1 = 0, sB1 = 0, dB1 = 0, pB1 = 0,
          sT = 0, dT = 0, pT = 0;
#pragma unroll
    for (int c = 0; c < 4; c++) {
        const float va = as_[c], vd = ad_[c], vm = Wm[c];
        const float w0 = Wg[c], w5 = Wg[5 * 4 + c], w12 = Wg[12 * 4 + c];
        sA1 = fmaf(w0, va, sA1);  dA1 = fmaf(w0, vd, dA1);  pA1 = fmaf(w0, vm, pA1);
        sB1 = fmaf(w5, va, sB1);  dB1 = fmaf(w5, vd, dB1);  pB1 = fmaf(w5, vm, pB1);
        sT  = fmaf(w12, va, sT);  dT  = fmaf(w12, vd, dT);  pT  = fmaf(w12, vm, pT);
    }

    const int cab = __float_as_int(cc.w);
    const float4 a4 = *(const float4*)(x + (cab & 0xffff) * T_TICKS + tg * TG);
    const float4 b4 = *(const float4*)(x + (cab >> 16) * T_TICKS + tg * TG);
    const float a[4] = {a4.x, a4.y, a4.z, a4.w};
    const float b[4] = {b4.x, b4.y, b4.z, b4.w};

    float dm[TG], tp[TG];
#pragma unroll
    for (int k = 0; k < TG; k++) {
        const float tk = (float)(tg * TG + k);
        dm[k] = cc.z + a[k] * dA1 + b[k] * dB1 + tk * dT + tk * sT;
        tp[k] = tk * pT;
    }
    float mx[TG], den[TG], pa[TG];
#pragma unroll
    for (int k = 0; k < TG; k++) { mx[k] = -INFINITY; den[k] = 0.f; pa[k] = 0.f; }

    for (int j = 0; j < deg; j += 4) {
        const int4 bb = *(const int4*)(bkt + j);
        const int m = deg - j;
        // clamp: loads unconditional & in-bounds even on poison slots
        const int s0 = min(max(bb.x, 0), NCROSS - 1);
        const int s1 = min(max(bb.y, 0), NCROSS - 1);
        const int s2 = min(max(bb.z, 0), NCROSS - 1);
        const int s3 = min(max(bb.w, 0), NCROSS - 1);
        const float4 cs0 = c4[s0];
        const float4 cs1 = c4[s1];
        const float4 cs2 = c4[s2];
        const float4 cs3 = c4[s3];
        const int i0 = __float_as_int(cs0.w);
        const int i1 = __float_as_int(cs1.w);
        const int i2 = __float_as_int(cs2.w);
        const int i3 = __float_as_int(cs3.w);
        const float4 xa0 = *(const float4*)(x + (i0 & 0xffff) * T_TICKS + tg * TG);
        const float4 xb0 = *(const float4*)(x + (i0 >> 16) * T_TICKS + tg * TG);
        const float4 xa1 = *(const float4*)(x + (i1 & 0xffff) * T_TICKS + tg * TG);
        const float4 xb1 = *(const float4*)(x + (i1 >> 16) * T_TICKS + tg * TG);
        const float4 xa2 = *(const float4*)(x + (i2 & 0xffff) * T_TICKS + tg * TG);
        const float4 xb2 = *(const float4*)(x + (i2 >> 16) * T_TICKS + tg * TG);
        const float4 xa3 = *(const float4*)(x + (i3 & 0xffff) * T_TICKS + tg * TG);
        const float4 xb3 = *(const float4*)(x + (i3 >> 16) * T_TICKS + tg * TG);
        edge_proc(true,  cs0, xa0, xb0, sA1, sB1, pA1, pB1, tp, dm, mx, den, pa);
        edge_proc(m > 1, cs1, xa1, xb1, sA1, sB1, pA1, pB1, tp, dm, mx, den, pa);
        edge_proc(m > 2, cs2, xa2, xb2, sA1, sB1, pA1, pB1, tp, dm, mx, den, pa);
        edge_proc(m > 3, cs3, xa3, xb3, sA1, sB1, pA1, pB1, tp, dm, mx, den, pa);
    }

    {
        const float bb2 = bm[0];
#pragma unroll
        for (int k = 0; k < TG; k++) {
            const float logit = pa[k] / (den[k] + 1e-9f) + bb2;
            lres[tgl * 4 + k][nq] = 1.f / (1.f + __expf(-logit));
        }
    }
    __syncthreads();

    // coalesced store: 128 rows x 16 cols; per wave instruction: 4 row-
    // segments of 64 B (sector-aligned, no write amplification).
    {
        const int col = tid & 15;
        const int rb  = (tid >> 4) * 4;
#pragma unroll
        for (int rr = 0; rr < 4; rr++) {
            const int row = rb + rr;
            out[(size_t)row * NCROSS + bbase + col] = lres[row][col];
        }
    }
}

// ---------------- launch ----------------

extern "C" void kernel_launch(void* const* d_in, const int* in_sizes, int n_in,
                              void* d_out, int out_size, void* d_ws, size_t ws_size,
                              hipStream_t stream) {
    const float* x   = (const float*)d_in[0];
    const int* c0  = (const int*)d_in[1];
    const int* c1  = (const int*)d_in[2];
    const int* c2  = (const int*)d_in[3];
    const int* g01 = (const int*)d_in[4];
    const int* g12 = (const int*)d_in[5];
    const int* g20 = (const int*)d_in[6];
    const float* r01 = (const float*)d_in[7];
    const float* r12 = (const float*)d_in[8];
    const float* r20 = (const float*)d_in[9];
    const int* edges = (const int*)d_in[10];          // [2, E]
    const float* Wg  = (const float*)d_in[11];
    const float* as_ = (const float*)d_in[12];
    const float* ad_ = (const float*)d_in[13];
    const float* bg  = (const float*)d_in[14];
    const float* Wm  = (const float*)d_in[15];
    const float* bm  = (const float*)d_in[16];
    float* out = (float*)d_out;

    const int* e_src = edges;
    const int* e_dst = edges + E_EDGES;

    // workspace layout (~4.5 MB total)
    char* ws = (char*)d_ws;
    size_t off = 0;
    int* counts = (int*)(ws + off); off += NCROSS * sizeof(int);
    off = (off + 255) & ~(size_t)255;
    int* bucket = (int*)(ws + off); off += (size_t)NCROSS * CAP * sizeof(int);  // 3.84 MB
    off = (off + 255) & ~(size_t)255;
    float4* c4 = (float4*)(ws + off); off += (size_t)NCROSS * sizeof(float4);   // 480 KB
    (void)ws_size; (void)n_in; (void)in_sizes; (void)out_size;

    hipMemsetAsync(counts, 0, NCROSS * sizeof(int), stream);

    k_prep<<<(PREP_ITEMS + 255) / 256, 256, 0, stream>>>(
        x, c0, c1, c2, g01, g12, g20, r01, r12, r20, Wg, bg, as_, ad_, Wm,
        e_src, e_dst, counts, bucket, c4);

    k_gat<<<NBLKN, 512, 0, stream>>>(x, c4, counts, bucket,
                                     Wg, as_, ad_, Wm, bm, out);
}